// Round 3
// baseline (730.853 us; speedup 1.0000x reference)
//
#include <hip/hip_runtime.h>
#include <hip/hip_bf16.h>
#include <math.h>

typedef __bf16 bf16;
typedef bf16 bf16x8 __attribute__((ext_vector_type(8)));
typedef bf16 bf16x4 __attribute__((ext_vector_type(4)));
typedef float f32x4 __attribute__((ext_vector_type(4)));

#define MFMA16(A,B,C) __builtin_amdgcn_mfma_f32_16x16x32_bf16(A,B,C,0,0,0)

static constexpr int QKV_ELEMS  = 768 * 256;
static constexpr int PROJ_ELEMS = 256 * 256;

// wave-local LDS ordering fence (stops compiler reordering; HW DS is in-order)
static __device__ __forceinline__ void lds_fence() {
    asm volatile("s_waitcnt lgkmcnt(0)" ::: "memory");
    __builtin_amdgcn_sched_barrier(0);
}

// pack two f32 -> one u32 of 2 bf16 (low = a, high = b); compiler fuses to cvt_pk
static __device__ __forceinline__ unsigned pack2(float a, float b) {
    bf16 xa = (bf16)a, xb = (bf16)b;
    unsigned short ua, ub;
    __builtin_memcpy(&ua, &xa, 2);
    __builtin_memcpy(&ub, &xb, 2);
    return (unsigned)ua | ((unsigned)ub << 16);
}

// Build an MFMA A/B fragment (bf16x8) from packed C-fragment registers.
// Target lane (hi,lo) element e needs src lane 32*(hi&1)+16*(e>>2)+lo, and
// register-set LOW (PKL*) for lanes<32, HIGH (PKH*) for lanes>=32.
#define BUILD_FRAG(dst, PKL0, PKL1, PKH0, PKH1)                               \
  {                                                                            \
    int sA = ((lane & 16) << 1) + lo;                                          \
    int sB = sA + 16;                                                          \
    int a0 = __shfl((int)(PKL0), sA), a1 = __shfl((int)(PKL1), sA);            \
    int a2 = __shfl((int)(PKL0), sB), a3 = __shfl((int)(PKL1), sB);            \
    int b0 = __shfl((int)(PKH0), sA), b1 = __shfl((int)(PKH1), sA);            \
    int b2 = __shfl((int)(PKH0), sB), b3 = __shfl((int)(PKH1), sB);            \
    union { int w[4]; bf16x8 v; } u_;                                          \
    bool uh_ = (lane >= 32);                                                   \
    u_.w[0] = uh_ ? b0 : a0; u_.w[1] = uh_ ? b1 : a1;                          \
    u_.w[2] = uh_ ? b2 : a2; u_.w[3] = uh_ ? b3 : a3;                          \
    dst = u_.v;                                                                \
  }

// ---- K0: cast weights fp32 -> bf16 into ws ----
__global__ void cvt_weights(const float* __restrict__ qkv_w,
                            const float* __restrict__ proj_w,
                            bf16* __restrict__ wq, bf16* __restrict__ wp) {
    int i = blockIdx.x * 256 + threadIdx.x;
    if (i < QKV_ELEMS) wq[i] = (bf16)qkv_w[i];
    int j = i - QKV_ELEMS;
    if (j >= 0 && j < PROJ_ELEMS) wp[j] = (bf16)proj_w[j];
}

// ---- fused: shift + QKV + window attention + proj + unshift ----
// 512 threads = 8 waves; wave w owns head w. One block per (batch, window).
__global__ __launch_bounds__(512, 4)
void swin_fused(const float* __restrict__ x,
                const bf16* __restrict__ wqkv,    // [768][256] bf16
                const bf16* __restrict__ wproj,   // [256][256] bf16
                const float* __restrict__ proj_b, // [256]
                const float* __restrict__ pose_g, // [15][15]
                float* __restrict__ out)
{
    // xbuf: x [64 tok][256 ch] bf16, chunk-swizzled; later overlaid with attn-out.
    __shared__ alignas(16) unsigned char xbuf[64 * 512];
    // per-wave vT [32 d][64 tok] bf16, swizzled
    __shared__ alignas(16) unsigned char vbufs[8][4096];
    __shared__ float pose[225];

    const int tid  = threadIdx.x;
    const int wave = tid >> 6, lane = tid & 63;
    const int hi   = lane >> 4, lo = lane & 15;
    const int b    = blockIdx.x >> 6;
    const int w    = blockIdx.x & 63;
    const int wh   = w >> 3, wwi = w & 7;
    const bool mlow = (wh == 7), mright = (wwi == 7);
    const f32x4 zero4 = {0.f, 0.f, 0.f, 0.f};

    if (tid < 225) pose[tid] = pose_g[tid];

    // ---- phase 0: x (cyclic shift -4,-4) -> LDS bf16, swizzled, dense loads ----
    {
        int tok = tid >> 3, j = tid & 7;
        int gy = ((wh << 3) + (tok >> 3) + 4) & 63;
        int gx = ((wwi << 3) + (tok & 7) + 4) & 63;
        const float* src = x + (((b << 6) + gy) * 64 + gx) * 256;
        #pragma unroll
        for (int f = 0; f < 8; ++f) {
            int c4 = f * 8 + j;                       // float4 index within row
            float4 v = *(const float4*)(src + c4 * 4);
            bf16x4 bv;
            bv[0] = (bf16)v.x; bv[1] = (bf16)v.y; bv[2] = (bf16)v.z; bv[3] = (bf16)v.w;
            int chunk = (c4 >> 1) ^ (tok & 7);
            *(bf16x4*)(xbuf + tok * 512 + (chunk << 4) + ((c4 & 1) << 3)) = bv;
        }
    }
    __syncthreads();

    unsigned char* vb = vbufs[wave];
    const int h = wave;

    // ===== QK-pass: [qk]^T = mfma(A = W rows (global), B = x rows (LDS)) =====
    // C[n][tok]: lane holds col tok = 16*Nt + lo, rows n = 16*Mt + 4*hi + r
    f32x4 acc[4][4];
    #pragma unroll
    for (int Mt = 0; Mt < 4; ++Mt)
        #pragma unroll
        for (int Nt = 0; Nt < 4; ++Nt) acc[Mt][Nt] = zero4;
    #pragma unroll
    for (int kk = 0; kk < 8; ++kk) {
        bf16x8 af[4], bx[4];
        #pragma unroll
        for (int Mt = 0; Mt < 4; ++Mt) {
            int wrow = (Mt >> 1) * 256 + h * 32 + ((Mt & 1) << 4) + lo;  // q | k
            af[Mt] = *(const bf16x8*)(wqkv + wrow * 256 + kk * 32 + hi * 8);
        }
        #pragma unroll
        for (int Nt = 0; Nt < 4; ++Nt) {
            int tok = Nt * 16 + lo;
            bx[Nt] = *(const bf16x8*)(xbuf + tok * 512 + (((kk * 4 + hi) ^ (tok & 7)) << 4));
        }
        #pragma unroll
        for (int Mt = 0; Mt < 4; ++Mt)
            #pragma unroll
            for (int Nt = 0; Nt < 4; ++Nt)
                acc[Mt][Nt] = MFMA16(af[Mt], bx[Nt], acc[Mt][Nt]);
    }
    // pack q,k C-fragments to bf16 pairs (register-resident, no LDS)
    unsigned pkQ[2][4][2], pkK[2][4][2];
    #pragma unroll
    for (int Mt = 0; Mt < 2; ++Mt)
        #pragma unroll
        for (int Nt = 0; Nt < 4; ++Nt)
            #pragma unroll
            for (int p = 0; p < 2; ++p) {
                pkQ[Mt][Nt][p] = pack2(acc[Mt][Nt][2 * p],     acc[Mt][Nt][2 * p + 1]);
                pkK[Mt][Nt][p] = pack2(acc[2 + Mt][Nt][2 * p], acc[2 + Mt][Nt][2 * p + 1]);
            }

    // ===== V-pass: v^T = mfma(W_v rows, x rows) -> vT in LDS =====
    {
        f32x4 accv[2][4];
        #pragma unroll
        for (int vm = 0; vm < 2; ++vm)
            #pragma unroll
            for (int Nt = 0; Nt < 4; ++Nt) accv[vm][Nt] = zero4;
        #pragma unroll
        for (int kk = 0; kk < 8; ++kk) {
            bf16x8 af[2], bx[4];
            #pragma unroll
            for (int vm = 0; vm < 2; ++vm) {
                int wrow = 512 + h * 32 + (vm << 4) + lo;
                af[vm] = *(const bf16x8*)(wqkv + wrow * 256 + kk * 32 + hi * 8);
            }
            #pragma unroll
            for (int Nt = 0; Nt < 4; ++Nt) {
                int tok = Nt * 16 + lo;
                bx[Nt] = *(const bf16x8*)(xbuf + tok * 512 + (((kk * 4 + hi) ^ (tok & 7)) << 4));
            }
            #pragma unroll
            for (int vm = 0; vm < 2; ++vm)
                #pragma unroll
                for (int Nt = 0; Nt < 4; ++Nt)
                    accv[vm][Nt] = MFMA16(af[vm], bx[Nt], accv[vm][Nt]);
        }
        // vT [d][tok] scalar scatter (wave-local)
        #pragma unroll
        for (int vm = 0; vm < 2; ++vm)
            #pragma unroll
            for (int Nt = 0; Nt < 4; ++Nt) {
                int tok = Nt * 16 + lo;
                #pragma unroll
                for (int r = 0; r < 4; ++r) {
                    int d = (vm << 4) + 4 * hi + r;
                    *(bf16*)(vb + d * 128 + (((tok >> 3) ^ (d & 7)) << 4) + ((tok & 7) << 1)) =
                        (bf16)accv[vm][Nt][r];
                }
            }
    }

    // ===== S^T = mfma(A = K-frag, B = Q-frag), frags via shfl =====
    bf16x8 kA[4];
    #pragma unroll
    for (int jt = 0; jt < 4; ++jt)
        BUILD_FRAG(kA[jt], pkK[0][jt][0], pkK[0][jt][1], pkK[1][jt][0], pkK[1][jt][1]);

    unsigned pkP[4][4][2];   // [jt][it][p] packed probabilities
    float rinv[4];
    const bool colmask_ = mright && (((lo & 7) >= 4) != (hi & 1));
    #pragma unroll
    for (int it = 0; it < 4; ++it) {
        bf16x8 qB;
        BUILD_FRAG(qB, pkQ[0][it][0], pkQ[0][it][1], pkQ[1][it][0], pkQ[1][it][1]);
        f32x4 s4[4];
        #pragma unroll
        for (int jt = 0; jt < 4; ++jt) s4[jt] = MFMA16(kA[jt], qB, zero4);

        float mx = -INFINITY;
        #pragma unroll
        for (int jt = 0; jt < 4; ++jt) {
            bool tilemask = mlow && ((it >= 2) != (jt >= 2));
            #pragma unroll
            for (int r = 0; r < 4; ++r) {
                int drow = 2 * jt + (hi >> 1) - 2 * it - (lo >> 3) + 7;
                int dcol = 4 * (hi & 1) + r - (lo & 7) + 7;
                float s = s4[jt][r] * 0.17677669529663687f + pose[drow * 15 + dcol];
                if (tilemask | colmask_) s = -INFINITY;
                s4[jt][r] = s;
                mx = fmaxf(mx, s);
            }
        }
        mx = fmaxf(mx, __shfl_xor(mx, 16));
        mx = fmaxf(mx, __shfl_xor(mx, 32));
        float sum = 0.f;
        #pragma unroll
        for (int jt = 0; jt < 4; ++jt)
            #pragma unroll
            for (int r = 0; r < 4; ++r) {
                float e = __expf(s4[jt][r] - mx);
                s4[jt][r] = e; sum += e;
            }
        sum += __shfl_xor(sum, 16);
        sum += __shfl_xor(sum, 32);
        rinv[it] = 1.0f / sum;
        #pragma unroll
        for (int jt = 0; jt < 4; ++jt)
            #pragma unroll
            for (int p = 0; p < 2; ++p)
                pkP[jt][it][p] = pack2(s4[jt][2 * p], s4[jt][2 * p + 1]);
    }

    // ===== PV^T = mfma(A = vT rows (LDS), B = P-frag (shfl)) =====
    f32x4 oacc[2][4];
    #pragma unroll
    for (int dMt = 0; dMt < 2; ++dMt)
        #pragma unroll
        for (int it = 0; it < 4; ++it) oacc[dMt][it] = zero4;
    lds_fence();   // vT stores ordered before va reads
    #pragma unroll
    for (int ks = 0; ks < 2; ++ks) {
        bf16x8 va[2];
        #pragma unroll
        for (int dMt = 0; dMt < 2; ++dMt) {
            int d = dMt * 16 + lo;
            va[dMt] = *(const bf16x8*)(vb + d * 128 + (((ks * 4 + hi) ^ (d & 7)) << 4));
        }
        #pragma unroll
        for (int it = 0; it < 4; ++it) {
            bf16x8 pB;
            BUILD_FRAG(pB, pkP[2 * ks][it][0], pkP[2 * ks][it][1],
                           pkP[2 * ks + 1][it][0], pkP[2 * ks + 1][it][1]);
            #pragma unroll
            for (int dMt = 0; dMt < 2; ++dMt)
                oacc[dMt][it] = MFMA16(va[dMt], pB, oacc[dMt][it]);
        }
    }

    // ---- all waves done reading x -> overlay attn-out into xbuf ----
    __syncthreads();
    #pragma unroll
    for (int dMt = 0; dMt < 2; ++dMt)
        #pragma unroll
        for (int it = 0; it < 4; ++it) {
            int tok = it * 16 + lo;
            bf16x4 v;
            #pragma unroll
            for (int r = 0; r < 4; ++r) v[r] = (bf16)(oacc[dMt][it][r] * rinv[it]);
            int chunk = ((h << 2) + (dMt << 1) + (hi >> 1)) ^ (tok & 7);
            *(bf16x4*)(xbuf + tok * 512 + (chunk << 4) + ((hi & 1) << 3)) = v;
        }
    __syncthreads();

    // ===== proj: out = ao * Wp^T + bias; wave w does out-ch 32w..32w+31 =====
    f32x4 pacc[4][2];
    #pragma unroll
    for (int Mt = 0; Mt < 4; ++Mt)
        #pragma unroll
        for (int nt = 0; nt < 2; ++nt) pacc[Mt][nt] = zero4;
    #pragma unroll
    for (int kk = 0; kk < 8; ++kk) {
        bf16x8 aA[4], bB[2];
        #pragma unroll
        for (int Mt = 0; Mt < 4; ++Mt) {
            int tok = Mt * 16 + lo;
            aA[Mt] = *(const bf16x8*)(xbuf + tok * 512 + (((kk * 4 + hi) ^ (tok & 7)) << 4));
        }
        #pragma unroll
        for (int nt = 0; nt < 2; ++nt) {
            int c = wave * 32 + nt * 16 + lo;
            bB[nt] = *(const bf16x8*)(wproj + c * 256 + kk * 32 + hi * 8);
        }
        #pragma unroll
        for (int Mt = 0; Mt < 4; ++Mt)
            #pragma unroll
            for (int nt = 0; nt < 2; ++nt)
                pacc[Mt][nt] = MFMA16(aA[Mt], bB[nt], pacc[Mt][nt]);
    }
    #pragma unroll
    for (int nt = 0; nt < 2; ++nt) {
        int c = wave * 32 + nt * 16 + lo;
        float pb2 = proj_b[c];
        #pragma unroll
        for (int Mt = 0; Mt < 4; ++Mt)
            #pragma unroll
            for (int r = 0; r < 4; ++r) {
                int tok = Mt * 16 + 4 * hi + r;
                int fy = ((wh << 3) + (tok >> 3) + 4) & 63;
                int fx = ((wwi << 3) + (tok & 7) + 4) & 63;
                out[(((b << 6) + fy) * 64 + fx) * 256 + c] = pacc[Mt][nt][r] + pb2;
            }
    }
}

extern "C" void kernel_launch(void* const* d_in, const int* in_sizes, int n_in,
                              void* d_out, int out_size, void* d_ws, size_t ws_size,
                              hipStream_t stream) {
    const float* x       = (const float*)d_in[0];
    const float* qkv_w   = (const float*)d_in[1];
    const float* proj_w  = (const float*)d_in[2];
    const float* proj_b  = (const float*)d_in[3];
    const float* pos_emb = (const float*)d_in[4];

    bf16* wq = (bf16*)d_ws;               // 768*256 bf16
    bf16* wp = wq + QKV_ELEMS;            // 256*256 bf16

    cvt_weights<<<dim3((QKV_ELEMS + PROJ_ELEMS) / 256), dim3(256), 0, stream>>>(
        qkv_w, proj_w, wq, wp);
    swin_fused<<<dim3(64 * 64), dim3(512), 0, stream>>>(
        x, wq, wp, proj_b, pos_emb, (float*)d_out);
}

// Round 4
// 671.492 us; speedup vs baseline: 1.0884x; 1.0884x over previous
//
#include <hip/hip_runtime.h>
#include <hip/hip_bf16.h>
#include <math.h>

typedef __bf16 bf16;
typedef bf16 bf16x8 __attribute__((ext_vector_type(8)));
typedef bf16 bf16x4 __attribute__((ext_vector_type(4)));
typedef float f32x4 __attribute__((ext_vector_type(4)));

#define MFMA16(A,B,C) __builtin_amdgcn_mfma_f32_16x16x32_bf16(A,B,C,0,0,0)

static constexpr int QKV_ELEMS  = 768 * 256;
static constexpr int PROJ_ELEMS = 256 * 256;

// wave-local LDS ordering fence (stops compiler reordering; waits DS completion)
static __device__ __forceinline__ void lds_fence() {
    asm volatile("s_waitcnt lgkmcnt(0)" ::: "memory");
    __builtin_amdgcn_sched_barrier(0);
}

// pack two f32 -> one u32 of 2 bf16 (low = a, high = b)
static __device__ __forceinline__ unsigned pack2(float a, float b) {
    bf16 xa = (bf16)a, xb = (bf16)b;
    unsigned short ua, ub;
    __builtin_memcpy(&ua, &xa, 2);
    __builtin_memcpy(&ub, &xb, 2);
    return (unsigned)ua | ((unsigned)ub << 16);
}

// Build an MFMA A/B fragment (bf16x8) from packed C-fragment registers.
// Dest lane (hi,lo) word w needs src lane 32*(hi&1)+16*(w>>1)+lo; register set
// LOW (PKL*) for dest lanes<32, HIGH (PKH*) for lanes>=32; p = w&1.
#define BUILD_FRAG(dst, PKL0, PKL1, PKH0, PKH1)                               \
  {                                                                            \
    int sA = ((lane & 16) << 1) + lo;                                          \
    int sB = sA + 16;                                                          \
    int a0 = __shfl((int)(PKL0), sA), a1 = __shfl((int)(PKL1), sA);            \
    int a2 = __shfl((int)(PKL0), sB), a3 = __shfl((int)(PKL1), sB);            \
    int b0 = __shfl((int)(PKH0), sA), b1 = __shfl((int)(PKH1), sA);            \
    int b2 = __shfl((int)(PKH0), sB), b3 = __shfl((int)(PKH1), sB);            \
    union { int w[4]; bf16x8 v; } u_;                                          \
    bool uh_ = (lane >= 32);                                                   \
    u_.w[0] = uh_ ? b0 : a0; u_.w[1] = uh_ ? b1 : a1;                          \
    u_.w[2] = uh_ ? b2 : a2; u_.w[3] = uh_ ? b3 : a3;                          \
    dst = u_.v;                                                                \
  }

// ---- K0: cast weights fp32 -> bf16 into ws ----
__global__ void cvt_weights(const float* __restrict__ qkv_w,
                            const float* __restrict__ proj_w,
                            bf16* __restrict__ wq, bf16* __restrict__ wp) {
    int i = blockIdx.x * 256 + threadIdx.x;
    if (i < QKV_ELEMS) wq[i] = (bf16)qkv_w[i];
    int j = i - QKV_ELEMS;
    if (j >= 0 && j < PROJ_ELEMS) wp[j] = (bf16)proj_w[j];
}

// ---- fused: shift + QKV + window attention + proj + unshift ----
// 512 threads = 8 waves; wave w owns head w. One block per (batch, window).
__global__ __launch_bounds__(512, 4)
void swin_fused(const float* __restrict__ x,
                const bf16* __restrict__ wqkv,    // [768][256] bf16
                const bf16* __restrict__ wproj,   // [256][256] bf16
                const float* __restrict__ proj_b, // [256]
                const float* __restrict__ pose_g, // [15][15]
                float* __restrict__ out)
{
    // xbuf: x [64 tok][256 ch] bf16, chunk-swizzled; later overlaid with attn-out.
    __shared__ alignas(16) unsigned char xbuf[64 * 512];
    // per-wave vT [32 d][64 tok] bf16, swizzled
    __shared__ alignas(16) unsigned char vbufs[8][4096];
    __shared__ float pose[225];

    const int tid  = threadIdx.x;
    const int wave = tid >> 6, lane = tid & 63;
    const int hi   = lane >> 4, lo = lane & 15;
    const int b    = blockIdx.x >> 6;
    const int w    = blockIdx.x & 63;
    const int wh   = w >> 3, wwi = w & 7;
    const bool mlow = (wh == 7), mright = (wwi == 7);
    const f32x4 zero4 = {0.f, 0.f, 0.f, 0.f};

    if (tid < 225) pose[tid] = pose_g[tid];

    // ---- phase 0: x (cyclic shift -4,-4) -> LDS bf16, swizzled, dense loads ----
    {
        int tok = tid >> 3, j = tid & 7;
        int gy = ((wh << 3) + (tok >> 3) + 4) & 63;
        int gx = ((wwi << 3) + (tok & 7) + 4) & 63;
        const float* src = x + (((b << 6) + gy) * 64 + gx) * 256;
        #pragma unroll
        for (int f = 0; f < 8; ++f) {
            int c4 = f * 8 + j;                       // float4 index within row
            float4 v = *(const float4*)(src + c4 * 4);
            bf16x4 bv;
            bv[0] = (bf16)v.x; bv[1] = (bf16)v.y; bv[2] = (bf16)v.z; bv[3] = (bf16)v.w;
            int chunk = (c4 >> 1) ^ (tok & 7);
            *(bf16x4*)(xbuf + tok * 512 + (chunk << 4) + ((c4 & 1) << 3)) = bv;
        }
    }
    __syncthreads();

    unsigned char* vb = vbufs[wave];
    const int h = wave;

    // ===== QK-pass: [qk]^T = mfma(A = W rows (global), B = x rows (LDS)) =====
    // C[n][tok]: lane holds col tok = 16*Nt + lo, rows n = 16*Mt + 4*hi + r
    unsigned pkQ[2][4][2];
    bf16x8 kA[4];
    {
        f32x4 acc[4][4];
        #pragma unroll
        for (int Mt = 0; Mt < 4; ++Mt)
            #pragma unroll
            for (int Nt = 0; Nt < 4; ++Nt) acc[Mt][Nt] = zero4;
        #pragma unroll
        for (int kk = 0; kk < 8; ++kk) {
            bf16x8 af[4], bx[4];
            #pragma unroll
            for (int Mt = 0; Mt < 4; ++Mt) {
                int wrow = (Mt >> 1) * 256 + h * 32 + ((Mt & 1) << 4) + lo;  // q | k
                af[Mt] = *(const bf16x8*)(wqkv + wrow * 256 + kk * 32 + hi * 8);
            }
            #pragma unroll
            for (int Nt = 0; Nt < 4; ++Nt) {
                int tok = Nt * 16 + lo;
                bx[Nt] = *(const bf16x8*)(xbuf + tok * 512 + (((kk * 4 + hi) ^ (tok & 7)) << 4));
            }
            #pragma unroll
            for (int Mt = 0; Mt < 4; ++Mt)
                #pragma unroll
                for (int Nt = 0; Nt < 4; ++Nt)
                    acc[Mt][Nt] = MFMA16(af[Mt], bx[Nt], acc[Mt][Nt]);
        }
        // pack q to registers; pack k and IMMEDIATELY build kA frags (pkK dies here)
        unsigned pkK[2][4][2];
        #pragma unroll
        for (int Mt = 0; Mt < 2; ++Mt)
            #pragma unroll
            for (int Nt = 0; Nt < 4; ++Nt)
                #pragma unroll
                for (int p = 0; p < 2; ++p) {
                    pkQ[Mt][Nt][p] = pack2(acc[Mt][Nt][2 * p],     acc[Mt][Nt][2 * p + 1]);
                    pkK[Mt][Nt][p] = pack2(acc[2 + Mt][Nt][2 * p], acc[2 + Mt][Nt][2 * p + 1]);
                }
        #pragma unroll
        for (int jt = 0; jt < 4; ++jt)
            BUILD_FRAG(kA[jt], pkK[0][jt][0], pkK[0][jt][1], pkK[1][jt][0], pkK[1][jt][1]);
    }

    // ===== V-pass: v^T = mfma(W_v rows, x rows) -> vT in LDS =====
    {
        f32x4 accv[2][4];
        #pragma unroll
        for (int vm = 0; vm < 2; ++vm)
            #pragma unroll
            for (int Nt = 0; Nt < 4; ++Nt) accv[vm][Nt] = zero4;
        #pragma unroll
        for (int kk = 0; kk < 8; ++kk) {
            bf16x8 af[2], bx[4];
            #pragma unroll
            for (int vm = 0; vm < 2; ++vm) {
                int wrow = 512 + h * 32 + (vm << 4) + lo;
                af[vm] = *(const bf16x8*)(wqkv + wrow * 256 + kk * 32 + hi * 8);
            }
            #pragma unroll
            for (int Nt = 0; Nt < 4; ++Nt) {
                int tok = Nt * 16 + lo;
                bx[Nt] = *(const bf16x8*)(xbuf + tok * 512 + (((kk * 4 + hi) ^ (tok & 7)) << 4));
            }
            #pragma unroll
            for (int vm = 0; vm < 2; ++vm)
                #pragma unroll
                for (int Nt = 0; Nt < 4; ++Nt)
                    accv[vm][Nt] = MFMA16(af[vm], bx[Nt], accv[vm][Nt]);
        }
        // vT [d][tok] scalar scatter (wave-local)
        #pragma unroll
        for (int vm = 0; vm < 2; ++vm)
            #pragma unroll
            for (int Nt = 0; Nt < 4; ++Nt) {
                int tok = Nt * 16 + lo;
                #pragma unroll
                for (int r = 0; r < 4; ++r) {
                    int d = (vm << 4) + 4 * hi + r;
                    *(bf16*)(vb + d * 128 + (((tok >> 3) ^ (d & 7)) << 4) + ((tok & 7) << 1)) =
                        (bf16)accv[vm][Nt][r];
                }
            }
    }
    lds_fence();   // vT stores complete before PV reads below

    // ===== merged S + softmax + PV, one 16-col tile (it) at a time =====
    // S^T = mfma(A = kA, B = qB); C[j][i]: lane col i = 16*it+lo, rows j = 16*jt+4*hi+r
    // PV^T = mfma(A = vT rows (LDS), B = P-frag (shfl)); oacc[dMt][it]
    f32x4 oacc[2][4];
    #pragma unroll
    for (int dMt = 0; dMt < 2; ++dMt)
        #pragma unroll
        for (int it = 0; it < 4; ++it) oacc[dMt][it] = zero4;
    float rinv[4];
    const bool colmask_ = mright && (((lo & 7) >= 4) != (hi & 1));
    #pragma unroll
    for (int it = 0; it < 4; ++it) {
        bf16x8 qB;
        BUILD_FRAG(qB, pkQ[0][it][0], pkQ[0][it][1], pkQ[1][it][0], pkQ[1][it][1]);
        f32x4 s4[4];
        #pragma unroll
        for (int jt = 0; jt < 4; ++jt) s4[jt] = MFMA16(kA[jt], qB, zero4);

        float mx = -INFINITY;
        #pragma unroll
        for (int jt = 0; jt < 4; ++jt) {
            bool tilemask = mlow && ((it >= 2) != (jt >= 2));
            #pragma unroll
            for (int r = 0; r < 4; ++r) {
                int drow = 2 * jt + (hi >> 1) - 2 * it - (lo >> 3) + 7;
                int dcol = 4 * (hi & 1) + r - (lo & 7) + 7;
                float s = s4[jt][r] * 0.17677669529663687f + pose[drow * 15 + dcol];
                if (tilemask | colmask_) s = -INFINITY;
                s4[jt][r] = s;
                mx = fmaxf(mx, s);
            }
        }
        mx = fmaxf(mx, __shfl_xor(mx, 16));
        mx = fmaxf(mx, __shfl_xor(mx, 32));
        float sum = 0.f;
        #pragma unroll
        for (int jt = 0; jt < 4; ++jt)
            #pragma unroll
            for (int r = 0; r < 4; ++r) {
                float e = __expf(s4[jt][r] - mx);
                s4[jt][r] = e; sum += e;
            }
        sum += __shfl_xor(sum, 16);
        sum += __shfl_xor(sum, 32);
        rinv[it] = 1.0f / sum;

        // pack this column-tile's P and consume it immediately (no pkP array)
        unsigned pk[4][2];
        #pragma unroll
        for (int jt = 0; jt < 4; ++jt)
            #pragma unroll
            for (int p = 0; p < 2; ++p)
                pk[jt][p] = pack2(s4[jt][2 * p], s4[jt][2 * p + 1]);
        #pragma unroll
        for (int ks = 0; ks < 2; ++ks) {
            bf16x8 pB;
            BUILD_FRAG(pB, pk[2 * ks][0], pk[2 * ks][1], pk[2 * ks + 1][0], pk[2 * ks + 1][1]);
            #pragma unroll
            for (int dMt = 0; dMt < 2; ++dMt) {
                int d = dMt * 16 + lo;
                bf16x8 va = *(const bf16x8*)(vb + d * 128 + (((ks * 4 + hi) ^ (d & 7)) << 4));
                oacc[dMt][it] = MFMA16(va, pB, oacc[dMt][it]);
            }
        }
    }

    // ---- all waves done reading x -> overlay attn-out into xbuf ----
    __syncthreads();
    #pragma unroll
    for (int dMt = 0; dMt < 2; ++dMt)
        #pragma unroll
        for (int it = 0; it < 4; ++it) {
            int tok = it * 16 + lo;
            bf16x4 v;
            #pragma unroll
            for (int r = 0; r < 4; ++r) v[r] = (bf16)(oacc[dMt][it][r] * rinv[it]);
            int chunk = ((h << 2) + (dMt << 1) + (hi >> 1)) ^ (tok & 7);
            *(bf16x4*)(xbuf + tok * 512 + (chunk << 4) + ((hi & 1) << 3)) = v;
        }
    __syncthreads();

    // ===== proj: out = ao * Wp^T + bias; wave w does out-ch 32w..32w+31 =====
    f32x4 pacc[4][2];
    #pragma unroll
    for (int Mt = 0; Mt < 4; ++Mt)
        #pragma unroll
        for (int nt = 0; nt < 2; ++nt) pacc[Mt][nt] = zero4;
    #pragma unroll
    for (int kk = 0; kk < 8; ++kk) {
        bf16x8 aA[4], bB[2];
        #pragma unroll
        for (int Mt = 0; Mt < 4; ++Mt) {
            int tok = Mt * 16 + lo;
            aA[Mt] = *(const bf16x8*)(xbuf + tok * 512 + (((kk * 4 + hi) ^ (tok & 7)) << 4));
        }
        #pragma unroll
        for (int nt = 0; nt < 2; ++nt) {
            int c = wave * 32 + nt * 16 + lo;
            bB[nt] = *(const bf16x8*)(wproj + c * 256 + kk * 32 + hi * 8);
        }
        #pragma unroll
        for (int Mt = 0; Mt < 4; ++Mt)
            #pragma unroll
            for (int nt = 0; nt < 2; ++nt)
                pacc[Mt][nt] = MFMA16(aA[Mt], bB[nt], pacc[Mt][nt]);
    }
    #pragma unroll
    for (int nt = 0; nt < 2; ++nt) {
        int c = wave * 32 + nt * 16 + lo;
        float pb2 = proj_b[c];
        #pragma unroll
        for (int Mt = 0; Mt < 4; ++Mt)
            #pragma unroll
            for (int r = 0; r < 4; ++r) {
                int tok = Mt * 16 + 4 * hi + r;
                int fy = ((wh << 3) + (tok >> 3) + 4) & 63;
                int fx = ((wwi << 3) + (tok & 7) + 4) & 63;
                out[(((b << 6) + fy) * 64 + fx) * 256 + c] = pacc[Mt][nt][r] + pb2;
            }
    }
}

extern "C" void kernel_launch(void* const* d_in, const int* in_sizes, int n_in,
                              void* d_out, int out_size, void* d_ws, size_t ws_size,
                              hipStream_t stream) {
    const float* x       = (const float*)d_in[0];
    const float* qkv_w   = (const float*)d_in[1];
    const float* proj_w  = (const float*)d_in[2];
    const float* proj_b  = (const float*)d_in[3];
    const float* pos_emb = (const float*)d_in[4];

    bf16* wq = (bf16*)d_ws;               // 768*256 bf16
    bf16* wp = wq + QKV_ELEMS;            // 256*256 bf16

    cvt_weights<<<dim3((QKV_ELEMS + PROJ_ELEMS) / 256), dim3(256), 0, stream>>>(
        qkv_w, proj_w, wq, wp);
    swin_fused<<<dim3(64 * 64), dim3(512), 0, stream>>>(
        x, wq, wp, proj_b, pos_emb, (float*)d_out);
}

// Round 5
// 657.173 us; speedup vs baseline: 1.1121x; 1.0218x over previous
//
#include <hip/hip_runtime.h>
#include <hip/hip_bf16.h>
#include <math.h>

typedef __bf16 bf16;
typedef bf16 bf16x8 __attribute__((ext_vector_type(8)));
typedef bf16 bf16x4 __attribute__((ext_vector_type(4)));
typedef float f32x4 __attribute__((ext_vector_type(4)));

#define MFMA16(A,B,C) __builtin_amdgcn_mfma_f32_16x16x32_bf16(A,B,C,0,0,0)

static constexpr int QKV_ELEMS  = 768 * 256;
static constexpr int PROJ_ELEMS = 256 * 256;

// wave-local LDS ordering fence (stops compiler reordering; waits DS completion)
static __device__ __forceinline__ void lds_fence() {
    asm volatile("s_waitcnt lgkmcnt(0)" ::: "memory");
    __builtin_amdgcn_sched_barrier(0);
}

// pack two f32 -> one u32 of 2 bf16 (low = a, high = b)
static __device__ __forceinline__ unsigned pack2(float a, float b) {
    bf16 xa = (bf16)a, xb = (bf16)b;
    unsigned short ua, ub;
    __builtin_memcpy(&ua, &xa, 2);
    __builtin_memcpy(&ub, &xb, 2);
    return (unsigned)ua | ((unsigned)ub << 16);
}

// Build an MFMA A/B fragment (bf16x8) from packed C-fragment registers.
// Dest lane (hi,lo) word w needs src lane 32*(hi&1)+16*(w>>1)+lo; register set
// LOW (PKL*) for dest lanes<32, HIGH (PKH*) for lanes>=32.
#define BUILD_FRAG(dst, PKL0, PKL1, PKH0, PKH1)                               \
  {                                                                            \
    int sA = ((lane & 16) << 1) + lo;                                          \
    int sB = sA + 16;                                                          \
    int a0 = __shfl((int)(PKL0), sA), a1 = __shfl((int)(PKL1), sA);            \
    int a2 = __shfl((int)(PKL0), sB), a3 = __shfl((int)(PKL1), sB);            \
    int b0 = __shfl((int)(PKH0), sA), b1 = __shfl((int)(PKH1), sA);            \
    int b2 = __shfl((int)(PKH0), sB), b3 = __shfl((int)(PKH1), sB);            \
    union { int w[4]; bf16x8 v; } u_;                                          \
    bool uh_ = (lane >= 32);                                                   \
    u_.w[0] = uh_ ? b0 : a0; u_.w[1] = uh_ ? b1 : a1;                          \
    u_.w[2] = uh_ ? b2 : a2; u_.w[3] = uh_ ? b3 : a3;                          \
    dst = u_.v;                                                                \
  }

// ---- K0: cast weights fp32 -> bf16 into ws ----
__global__ void cvt_weights(const float* __restrict__ qkv_w,
                            const float* __restrict__ proj_w,
                            bf16* __restrict__ wq, bf16* __restrict__ wp) {
    int i = blockIdx.x * 256 + threadIdx.x;
    if (i < QKV_ELEMS) wq[i] = (bf16)qkv_w[i];
    int j = i - QKV_ELEMS;
    if (j >= 0 && j < PROJ_ELEMS) wp[j] = (bf16)proj_w[j];
}

// ---- fused: shift + QKV + window attention + proj + unshift ----
// 256 threads = 4 waves; wave w owns heads 2w and 2w+1 (sequential).
// One block per (batch, window). grid = 64*64.
__global__ __launch_bounds__(256, 3)
void swin_fused(const float* __restrict__ x,
                const bf16* __restrict__ wqkv,    // [768][256] bf16
                const bf16* __restrict__ wproj,   // [256][256] bf16
                const float* __restrict__ proj_b, // [256]
                const float* __restrict__ pose_g, // [15][15]
                float* __restrict__ out)
{
    // xbuf: x [64 tok][256 ch] bf16, chunk-swizzled; later overlaid with attn-out.
    __shared__ alignas(16) unsigned char xbuf[64 * 512];
    // per-wave vT [32 d][64 tok] bf16, swizzled (reused across the 2 heads)
    __shared__ alignas(16) unsigned char vbufs[4][4096];
    __shared__ float pose[225];

    const int tid  = threadIdx.x;
    const int wave = tid >> 6, lane = tid & 63;
    const int hi   = lane >> 4, lo = lane & 15;
    const int b    = blockIdx.x >> 6;
    const int w    = blockIdx.x & 63;
    const int wh   = w >> 3, wwi = w & 7;
    const bool mlow = (wh == 7), mright = (wwi == 7);
    const f32x4 zero4 = {0.f, 0.f, 0.f, 0.f};

    if (tid < 225) pose[tid] = pose_g[tid];

    // ---- phase 0: x (cyclic shift -4,-4) -> LDS bf16, swizzled, dense loads ----
    {
        int tok = tid >> 2, j = tid & 3;
        int gy = ((wh << 3) + (tok >> 3) + 4) & 63;
        int gx = ((wwi << 3) + (tok & 7) + 4) & 63;
        const float* src = x + (((b << 6) + gy) * 64 + gx) * 256;
        #pragma unroll
        for (int f = 0; f < 16; ++f) {
            int c4 = f * 4 + j;                       // float4 index within row
            float4 v = *(const float4*)(src + c4 * 4);
            bf16x4 bv;
            bv[0] = (bf16)v.x; bv[1] = (bf16)v.y; bv[2] = (bf16)v.z; bv[3] = (bf16)v.w;
            int chunk = (c4 >> 1) ^ (tok & 7);
            *(bf16x4*)(xbuf + tok * 512 + (chunk << 4) + ((c4 & 1) << 3)) = bv;
        }
    }
    __syncthreads();

    unsigned char* vb = vbufs[wave];
    unsigned pkO[2][2][4][2];   // [hp][dMt][it][p] packed attn-out stash
    const bool colmask_ = mright && (((lo & 7) >= 4) != (hi & 1));

    #pragma unroll 1
    for (int hp = 0; hp < 2; ++hp) {
        const int h = 2 * wave + hp;

        // ===== QK-pass: [qk]^T = mfma(A = W rows (global), B = x rows (LDS)) =====
        // C[n][tok]: lane holds col tok = 16*Nt + lo, rows n = 16*Mt + 4*hi + r
        unsigned pkQ[2][4][2];
        bf16x8 kA[4];
        {
            f32x4 acc[4][4];
            #pragma unroll
            for (int Mt = 0; Mt < 4; ++Mt)
                #pragma unroll
                for (int Nt = 0; Nt < 4; ++Nt) acc[Mt][Nt] = zero4;
            #pragma unroll
            for (int kk = 0; kk < 8; ++kk) {
                bf16x8 af[4], bx[4];
                #pragma unroll
                for (int Mt = 0; Mt < 4; ++Mt) {
                    int wrow = (Mt >> 1) * 256 + h * 32 + ((Mt & 1) << 4) + lo;  // q | k
                    af[Mt] = *(const bf16x8*)(wqkv + wrow * 256 + kk * 32 + hi * 8);
                }
                #pragma unroll
                for (int Nt = 0; Nt < 4; ++Nt) {
                    int tok = Nt * 16 + lo;
                    bx[Nt] = *(const bf16x8*)(xbuf + tok * 512 + (((kk * 4 + hi) ^ (tok & 7)) << 4));
                }
                #pragma unroll
                for (int Mt = 0; Mt < 4; ++Mt)
                    #pragma unroll
                    for (int Nt = 0; Nt < 4; ++Nt)
                        acc[Mt][Nt] = MFMA16(af[Mt], bx[Nt], acc[Mt][Nt]);
            }
            // pack q; pack k and IMMEDIATELY build kA frags (pkK dies here)
            unsigned pkK[2][4][2];
            #pragma unroll
            for (int Mt = 0; Mt < 2; ++Mt)
                #pragma unroll
                for (int Nt = 0; Nt < 4; ++Nt)
                    #pragma unroll
                    for (int p = 0; p < 2; ++p) {
                        pkQ[Mt][Nt][p] = pack2(acc[Mt][Nt][2 * p],     acc[Mt][Nt][2 * p + 1]);
                        pkK[Mt][Nt][p] = pack2(acc[2 + Mt][Nt][2 * p], acc[2 + Mt][Nt][2 * p + 1]);
                    }
            #pragma unroll
            for (int jt = 0; jt < 4; ++jt)
                BUILD_FRAG(kA[jt], pkK[0][jt][0], pkK[0][jt][1], pkK[1][jt][0], pkK[1][jt][1]);
        }

        // ===== V-pass: v^T = mfma(W_v rows, x rows) -> vT in LDS =====
        {
            f32x4 accv[2][4];
            #pragma unroll
            for (int vm = 0; vm < 2; ++vm)
                #pragma unroll
                for (int Nt = 0; Nt < 4; ++Nt) accv[vm][Nt] = zero4;
            #pragma unroll
            for (int kk = 0; kk < 8; ++kk) {
                bf16x8 af[2], bx[4];
                #pragma unroll
                for (int vm = 0; vm < 2; ++vm) {
                    int wrow = 512 + h * 32 + (vm << 4) + lo;
                    af[vm] = *(const bf16x8*)(wqkv + wrow * 256 + kk * 32 + hi * 8);
                }
                #pragma unroll
                for (int Nt = 0; Nt < 4; ++Nt) {
                    int tok = Nt * 16 + lo;
                    bx[Nt] = *(const bf16x8*)(xbuf + tok * 512 + (((kk * 4 + hi) ^ (tok & 7)) << 4));
                }
                #pragma unroll
                for (int vm = 0; vm < 2; ++vm)
                    #pragma unroll
                    for (int Nt = 0; Nt < 4; ++Nt)
                        accv[vm][Nt] = MFMA16(af[vm], bx[Nt], accv[vm][Nt]);
            }
            // hp=1 writes must not overtake hp=0's pending PV reads of vb
            lds_fence();
            // vT [d][tok] scalar scatter (wave-local)
            #pragma unroll
            for (int vm = 0; vm < 2; ++vm)
                #pragma unroll
                for (int Nt = 0; Nt < 4; ++Nt) {
                    int tok = Nt * 16 + lo;
                    #pragma unroll
                    for (int r = 0; r < 4; ++r) {
                        int d = (vm << 4) + 4 * hi + r;
                        *(bf16*)(vb + d * 128 + (((tok >> 3) ^ (d & 7)) << 4) + ((tok & 7) << 1)) =
                            (bf16)accv[vm][Nt][r];
                    }
                }
        }
        lds_fence();   // vT stores complete before PV reads below

        // ===== merged S + softmax + PV, one 16-col tile (it) at a time =====
        f32x4 oacc[2][4];
        #pragma unroll
        for (int dMt = 0; dMt < 2; ++dMt)
            #pragma unroll
            for (int it = 0; it < 4; ++it) oacc[dMt][it] = zero4;
        float rinv[4];
        #pragma unroll
        for (int it = 0; it < 4; ++it) {
            bf16x8 qB;
            BUILD_FRAG(qB, pkQ[0][it][0], pkQ[0][it][1], pkQ[1][it][0], pkQ[1][it][1]);
            f32x4 s4[4];
            #pragma unroll
            for (int jt = 0; jt < 4; ++jt) s4[jt] = MFMA16(kA[jt], qB, zero4);

            float mx = -INFINITY;
            #pragma unroll
            for (int jt = 0; jt < 4; ++jt) {
                bool tilemask = mlow && ((it >= 2) != (jt >= 2));
                #pragma unroll
                for (int r = 0; r < 4; ++r) {
                    int drow = 2 * jt + (hi >> 1) - 2 * it - (lo >> 3) + 7;
                    int dcol = 4 * (hi & 1) + r - (lo & 7) + 7;
                    float s = s4[jt][r] * 0.17677669529663687f + pose[drow * 15 + dcol];
                    if (tilemask | colmask_) s = -INFINITY;
                    s4[jt][r] = s;
                    mx = fmaxf(mx, s);
                }
            }
            mx = fmaxf(mx, __shfl_xor(mx, 16));
            mx = fmaxf(mx, __shfl_xor(mx, 32));
            float sum = 0.f;
            #pragma unroll
            for (int jt = 0; jt < 4; ++jt)
                #pragma unroll
                for (int r = 0; r < 4; ++r) {
                    float e = __expf(s4[jt][r] - mx);
                    s4[jt][r] = e; sum += e;
                }
            sum += __shfl_xor(sum, 16);
            sum += __shfl_xor(sum, 32);
            rinv[it] = 1.0f / sum;

            // pack this column-tile's P and consume it immediately
            unsigned pk[4][2];
            #pragma unroll
            for (int jt = 0; jt < 4; ++jt)
                #pragma unroll
                for (int p = 0; p < 2; ++p)
                    pk[jt][p] = pack2(s4[jt][2 * p], s4[jt][2 * p + 1]);
            #pragma unroll
            for (int ks = 0; ks < 2; ++ks) {
                bf16x8 pB;
                BUILD_FRAG(pB, pk[2 * ks][0], pk[2 * ks][1], pk[2 * ks + 1][0], pk[2 * ks + 1][1]);
                #pragma unroll
                for (int dMt = 0; dMt < 2; ++dMt) {
                    int d = dMt * 16 + lo;
                    bf16x8 va = *(const bf16x8*)(vb + d * 128 + (((ks * 4 + hi) ^ (d & 7)) << 4));
                    oacc[dMt][it] = MFMA16(va, pB, oacc[dMt][it]);
                }
            }
        }
        // fold 1/sum and stash packed (16 regs per head)
        #pragma unroll
        for (int dMt = 0; dMt < 2; ++dMt)
            #pragma unroll
            for (int it = 0; it < 4; ++it) {
                float r0 = oacc[dMt][it][0] * rinv[it], r1 = oacc[dMt][it][1] * rinv[it];
                float r2 = oacc[dMt][it][2] * rinv[it], r3 = oacc[dMt][it][3] * rinv[it];
                if (hp == 0) { pkO[0][dMt][it][0] = pack2(r0, r1); pkO[0][dMt][it][1] = pack2(r2, r3); }
                else         { pkO[1][dMt][it][0] = pack2(r0, r1); pkO[1][dMt][it][1] = pack2(r2, r3); }
            }
    }

    // ---- all waves done reading x -> overlay attn-out into xbuf ----
    __syncthreads();
    #pragma unroll
    for (int hp = 0; hp < 2; ++hp) {
        int h = 2 * wave + hp;
        #pragma unroll
        for (int dMt = 0; dMt < 2; ++dMt)
            #pragma unroll
            for (int it = 0; it < 4; ++it) {
                int tok = it * 16 + lo;
                union { unsigned u[2]; bf16x4 v; } uv;
                uv.u[0] = pkO[hp][dMt][it][0];
                uv.u[1] = pkO[hp][dMt][it][1];
                int chunk = ((h << 2) + (dMt << 1) + (hi >> 1)) ^ (tok & 7);
                *(bf16x4*)(xbuf + tok * 512 + (chunk << 4) + ((hi & 1) << 3)) = uv.v;
            }
    }
    __syncthreads();

    // ===== proj: out = ao * Wp^T + bias; wave w does out-ch 64w..64w+63 =====
    f32x4 pacc[4][4];
    #pragma unroll
    for (int Mt = 0; Mt < 4; ++Mt)
        #pragma unroll
        for (int nt = 0; nt < 4; ++nt) pacc[Mt][nt] = zero4;
    #pragma unroll
    for (int kk = 0; kk < 8; ++kk) {
        bf16x8 aA[4], bB[4];
        #pragma unroll
        for (int Mt = 0; Mt < 4; ++Mt) {
            int tok = Mt * 16 + lo;
            aA[Mt] = *(const bf16x8*)(xbuf + tok * 512 + (((kk * 4 + hi) ^ (tok & 7)) << 4));
        }
        #pragma unroll
        for (int nt = 0; nt < 4; ++nt) {
            int c = wave * 64 + nt * 16 + lo;
            bB[nt] = *(const bf16x8*)(wproj + c * 256 + kk * 32 + hi * 8);
        }
        #pragma unroll
        for (int Mt = 0; Mt < 4; ++Mt)
            #pragma unroll
            for (int nt = 0; nt < 4; ++nt)
                pacc[Mt][nt] = MFMA16(aA[Mt], bB[nt], pacc[Mt][nt]);
    }
    #pragma unroll
    for (int nt = 0; nt < 4; ++nt) {
        int c = wave * 64 + nt * 16 + lo;
        float pb2 = proj_b[c];
        #pragma unroll
        for (int Mt = 0; Mt < 4; ++Mt)
            #pragma unroll
            for (int r = 0; r < 4; ++r) {
                int tok = Mt * 16 + 4 * hi + r;
                int fy = ((wh << 3) + (tok >> 3) + 4) & 63;
                int fx = ((wwi << 3) + (tok & 7) + 4) & 63;
                out[(((b << 6) + fy) * 64 + fx) * 256 + c] = pacc[Mt][nt][r] + pb2;
            }
    }
}

extern "C" void kernel_launch(void* const* d_in, const int* in_sizes, int n_in,
                              void* d_out, int out_size, void* d_ws, size_t ws_size,
                              hipStream_t stream) {
    const float* x       = (const float*)d_in[0];
    const float* qkv_w   = (const float*)d_in[1];
    const float* proj_w  = (const float*)d_in[2];
    const float* proj_b  = (const float*)d_in[3];
    const float* pos_emb = (const float*)d_in[4];

    bf16* wq = (bf16*)d_ws;               // 768*256 bf16
    bf16* wp = wq + QKV_ELEMS;            // 256*256 bf16

    cvt_weights<<<dim3((QKV_ELEMS + PROJ_ELEMS) / 256), dim3(256), 0, stream>>>(
        qkv_w, proj_w, wq, wp);
    swin_fused<<<dim3(64 * 64), dim3(256), 0, stream>>>(
        x, wq, wp, proj_b, pos_emb, (float*)d_out);
}